// Round 9
// baseline (1038.814 us; speedup 1.0000x reference)
//
#include <hip/hip_runtime.h>
#include <stdint.h>

#define D_MODEL 1024
#define NUM_HEADS 16
#define HEAD_DIM 64
#define BATCH 4
#define SEQ 2048
#define BS (BATCH*SEQ)                    // 8192 rows
#define NX ((size_t)BS*D_MODEL)           // 8388608 elements
#define WELEMS ((size_t)D_MODEL*D_MODEL)  // 1048576 elements

typedef short bf16x8 __attribute__((ext_vector_type(8)));
typedef short bf16x4 __attribute__((ext_vector_type(4)));
typedef float f32x4  __attribute__((ext_vector_type(4)));
typedef float f32x16 __attribute__((ext_vector_type(16)));

__device__ inline float b2f(short u) {
  unsigned x = ((unsigned)(unsigned short)u) << 16;
  union { unsigned u; float f; } c; c.u = x; return c.f;
}
__device__ inline short f2b(float f) {
  union { float f; unsigned u; } c; c.f = f;
  unsigned r = (c.u + 0x7FFFu + ((c.u >> 16) & 1u)) >> 16;
  return (short)r;
}
__device__ inline unsigned cvt_pk(float lo, float hi) {
  unsigned r;
  asm("v_cvt_pk_bf16_f32 %0, %1, %2" : "=v"(r) : "v"(lo), "v"(hi));
  return r;
}
// dst row1 (lanes 32-63) <-> src row0 (lanes 0-31); both operands modified.
__device__ inline void pl32swap(unsigned &a, unsigned &b) {
  asm("v_permlane32_swap_b32 %0, %1" : "+v"(a), "+v"(b));
}

typedef const __attribute__((address_space(1))) void* gas_t;
typedef __attribute__((address_space(3))) void*       las_t;
__device__ inline void gload16(const void* g, void* l) {
  __builtin_amdgcn_global_load_lds((gas_t)(uintptr_t)g,
                                   (las_t)(uint32_t)(uintptr_t)l, 16, 0, 0);
}

// ---------------------------------------------------------------- prep
__global__ __launch_bounds__(256) void prep_convert(
    const float* __restrict__ X,
    const float* __restrict__ Wq, const float* __restrict__ Wk,
    const float* __restrict__ Wv, const float* __restrict__ Wo,
    short* __restrict__ Xb, short* __restrict__ Wb)
{
  size_t i = ((size_t)blockIdx.x * 256 + threadIdx.x) * 4;
  const float* src; short* dst; size_t off;
  if (i < NX) { src = X; dst = Xb; off = i; }
  else {
    size_t wi = i - NX;
    int w = (int)(wi >> 20);
    off = wi & (WELEMS - 1);
    src = (w == 0) ? Wq : (w == 1) ? Wk : (w == 2) ? Wv : Wo;
    dst = Wb + (size_t)w * WELEMS;
  }
  float4 v = *(const float4*)(src + off);
  bf16x4 o;
  o[0] = f2b(v.x); o[1] = f2b(v.y); o[2] = f2b(v.z); o[3] = f2b(v.w);
  *(bf16x4*)(dst + off) = o;
}

__global__ __launch_bounds__(256) void rope_table(
    const int* __restrict__ pos, float2* __restrict__ tab)
{
  int idx = blockIdx.x * 256 + threadIdx.x;   // 65536 total
  int s = idx >> 5, i = idx & 31;
  float p = (float)pos[s];
  float inv = exp2f(-0.41524101186098287f * (float)i);
  float a = p * inv;
  tab[idx] = make_float2(cosf(a), sinf(a));
}

// ---------------------------------------------------------------- GEMM
template<bool BF16OUT>
__global__ __launch_bounds__(256) void gemm_bt(
    const short* __restrict__ A, const short* __restrict__ Bw,
    void* __restrict__ outv, const int M, const int N, const int K,
    const size_t strideB, const size_t strideOut)
{
  __shared__ short Ash[128 * 32];
  __shared__ short Bsh[128 * 32];
  const int tid = threadIdx.x;
  const int wid = tid >> 6, lane = tid & 63;
  const int g = lane >> 4, li = lane & 15;
  const int row0 = blockIdx.y * 128, col0 = blockIdx.x * 128;
  const int wr = wid >> 1, wc = wid & 1;
  const short* Bz = Bw + (size_t)blockIdx.z * strideB;

  const short* Ag = A  + (size_t)(row0 + wid * 32 + (lane >> 2)) * K + (lane & 3) * 8;
  const short* Bg = Bz + (size_t)(col0 + wid * 32 + (lane >> 2)) * K + (lane & 3) * 8;
  short* lA = &Ash[wid * 1024];
  short* lB = &Bsh[wid * 1024];

  f32x4 acc[4][4];
#pragma unroll
  for (int i = 0; i < 4; ++i)
#pragma unroll
    for (int j = 0; j < 4; ++j) acc[i][j] = (f32x4){0.f, 0.f, 0.f, 0.f};

  for (int kt = 0; kt < K; kt += 32) {
    gload16(Ag + kt,                 lA);
    gload16(Ag + kt + (size_t)16*K,  lA + 512);
    gload16(Bg + kt,                 lB);
    gload16(Bg + kt + (size_t)16*K,  lB + 512);
    __syncthreads();
    bf16x8 af[4], bfv[4];
#pragma unroll
    for (int mm = 0; mm < 4; ++mm)
      af[mm] = *(const bf16x8*)&Ash[(wr * 64 + mm * 16 + li) * 32 + g * 8];
#pragma unroll
    for (int nn = 0; nn < 4; ++nn)
      bfv[nn] = *(const bf16x8*)&Bsh[(wc * 64 + nn * 16 + li) * 32 + g * 8];
#pragma unroll
    for (int mm = 0; mm < 4; ++mm)
#pragma unroll
      for (int nn = 0; nn < 4; ++nn)
        acc[mm][nn] = __builtin_amdgcn_mfma_f32_16x16x32_bf16(
            af[mm], bfv[nn], acc[mm][nn], 0, 0, 0);
    __syncthreads();
  }

  if (BF16OUT) {
    short* out = (short*)outv + (size_t)blockIdx.z * strideOut;
#pragma unroll
    for (int mm = 0; mm < 4; ++mm)
#pragma unroll
      for (int nn = 0; nn < 4; ++nn)
#pragma unroll
        for (int j = 0; j < 4; ++j) {
          int r = row0 + wr * 64 + mm * 16 + g * 4 + j;
          int c = col0 + wc * 64 + nn * 16 + li;
          out[(size_t)r * N + c] = f2b(acc[mm][nn][j]);
        }
  } else {
    float* out = (float*)outv;
#pragma unroll
    for (int mm = 0; mm < 4; ++mm)
#pragma unroll
      for (int nn = 0; nn < 4; ++nn)
#pragma unroll
        for (int j = 0; j < 4; ++j) {
          int r = row0 + wr * 64 + mm * 16 + g * 4 + j;
          int c = col0 + wc * 64 + nn * 16 + li;
          out[(size_t)r * N + c] = acc[mm][nn][j];
        }
  }
}

// ---------------------------------------------------------------- RoPE
__global__ __launch_bounds__(256) void rope_apply(
    short* __restrict__ QK, const float2* __restrict__ tab)
{
  size_t idx = (size_t)blockIdx.x * 256 + threadIdx.x;
  short* base = QK + (size_t)blockIdx.y * NX + idx * 8;
  size_t e = idx * 8;
  int s  = (int)((e >> 10) & (SEQ - 1));
  int dd = (int)(e & (D_MODEL - 1));
  int i0 = (dd & 63) >> 1;
  const float2* tp = tab + s * 32 + i0;
  bf16x8 v = *(bf16x8*)base;
#pragma unroll
  for (int k = 0; k < 4; ++k) {
    float2 cs = tp[k];
    float ev = b2f(v[2 * k]), ov = b2f(v[2 * k + 1]);
    v[2 * k]     = f2b(ev * cs.x - ov * cs.y);
    v[2 * k + 1] = f2b(ev * cs.y + ov * cs.x);
  }
  *(bf16x8*)base = v;
}

// ---------------------------------------------------------------- V^T
__global__ __launch_bounds__(256) void transpose_v(
    const short* __restrict__ V, short* __restrict__ Vt)
{
  __shared__ short tile[64][72];
  const int s0 = blockIdx.x * 64, h = blockIdx.y, b = blockIdx.z;
  const int t = threadIdx.x;
  const short* src = V + ((size_t)(b * SEQ + s0)) * D_MODEL + h * 64;
#pragma unroll
  for (int it = 0; it < 2; ++it) {
    int r = it * 32 + (t >> 3), c0 = (t & 7) * 8;
    *(bf16x8*)&tile[r][c0] = *(const bf16x8*)(src + (size_t)r * D_MODEL + c0);
  }
  __syncthreads();
  short* dst = Vt + ((size_t)(b * NUM_HEADS + h) * 64) * SEQ + s0;
#pragma unroll
  for (int it = 0; it < 2; ++it) {
    int d = it * 32 + (t >> 3), sOff = (t & 7) * 8;
    bf16x8 v;
#pragma unroll
    for (int j = 0; j < 8; ++j) v[j] = tile[sOff + j][d];
    *(bf16x8*)(dst + (size_t)d * SEQ + sOff) = v;
  }
}

// ---------------------------------------------------------------- flash v6
// = v5 structure (32x32 swapped MFMA, in-register softmax, permlane P
// redistribution) with launch_bounds relaxed (256,3): v5's (256,4) forced
// VGPR<=64 against ~120 demand -> scratch spills (WRITE_SIZE +7MB, 5x dur).
#define EXPSCALE 0.18033688011112043f   // log2(e) / sqrt(64)
#define MASKV   -30000.0f

__global__ __launch_bounds__(256, 3) void flash_attn(
    const short* __restrict__ Q, const short* __restrict__ K,
    const short* __restrict__ Vt, short* __restrict__ O)
{
  __shared__ short Ksh[2][64 * 64];   // 8KB per buf
  __shared__ short Vsh[2][64 * 64];
  const int qtb = 15 - (int)blockIdx.x;            // long blocks first
  const int h = blockIdx.y, b = blockIdx.z;
  const int tid = threadIdx.x;
  const int wid = tid >> 6, lane = tid & 63;
  const int q5 = lane & 31, hi = lane >> 5;
  const int qrow0 = qtb * 128 + wid * 32;
  const int tmaxBlk = 2 * qtb + 1;
  const int wtmax = (qrow0 + 31) >> 6;
  const size_t bS = (size_t)b * SEQ;

  const short* Kb = K  + bS * D_MODEL + h * 64;
  const short* Vb = Vt + (size_t)(b * NUM_HEADS + h) * 64 * SEQ;

  // staging geometry (pre-swizzled global source; LDS dest linear)
  const int srr = lane >> 3;               // 0..7
  const int cs  = (lane & 7) ^ srr;        // source chunk
  const int rB  = wid * 8 + srr;

#define STAGE(buf, t) {                                                      \
    const size_t kr0 = (size_t)((t) * 64 + rB) * D_MODEL + cs * 8;           \
    const size_t kr1 = (size_t)((t) * 64 + rB + 32) * D_MODEL + cs * 8;      \
    gload16(Kb + kr0, &Ksh[buf][(wid * 8) * 64]);                            \
    gload16(Kb + kr1, &Ksh[buf][(32 + wid * 8) * 64]);                       \
    const size_t vr0 = (size_t)rB * SEQ + (t) * 64 + cs * 8;                 \
    const size_t vr1 = (size_t)(rB + 32) * SEQ + (t) * 64 + cs * 8;          \
    gload16(Vb + vr0, &Vsh[buf][(wid * 8) * 64]);                            \
    gload16(Vb + vr1, &Vsh[buf][(32 + wid * 8) * 64]);                       \
  }

  // Q B-frags: qb[dblk][e] = Q[qrow0+q5][dblk*16 + 8*hi + e]
  bf16x8 qb[4];
  {
    const short* Qp = Q + (bS + qrow0 + q5) * D_MODEL + h * 64 + hi * 8;
#pragma unroll
    for (int d = 0; d < 4; ++d) qb[d] = *(const bf16x8*)(Qp + d * 16);
  }

  f32x16 acc0, acc1;
#pragma unroll
  for (int r = 0; r < 16; ++r) { acc0[r] = 0.f; acc1[r] = 0.f; }
  float mrow = MASKV, lrow = 0.f;

  STAGE(0, 0);
  __syncthreads();

  for (int t = 0; t <= tmaxBlk; ++t) {
    const int cur = t & 1;
    if (t < tmaxBlk) STAGE(cur ^ 1, t + 1);

    if (t <= wtmax) {
      const short* Kc = &Ksh[cur][0];
      const short* Vc = &Vsh[cur][0];
      const bool diag = (t == wtmax);
      const bool full = !diag || (wid & 1);   // even waves: n=1 all-masked

      // ---- QK^T: sc[n] = S^T rows k=32n.., col q
      f32x16 sc0, sc1;
#pragma unroll
      for (int r = 0; r < 16; ++r) { sc0[r] = 0.f; sc1[r] = 0.f; }
      __builtin_amdgcn_s_setprio(1);
#pragma unroll
      for (int d = 0; d < 4; ++d) {
        bf16x8 ak = *(const bf16x8*)&Kc[q5 * 64 + (((2 * d + hi) ^ (q5 & 7)) << 3)];
        sc0 = __builtin_amdgcn_mfma_f32_32x32x16_bf16(ak, qb[d], sc0, 0, 0, 0);
      }
      if (full) {
#pragma unroll
        for (int d = 0; d < 4; ++d) {
          bf16x8 ak = *(const bf16x8*)&Kc[(32 + q5) * 64 + (((2 * d + hi) ^ (q5 & 7)) << 3)];
          sc1 = __builtin_amdgcn_mfma_f32_32x32x16_bf16(ak, qb[d], sc1, 0, 0, 0);
        }
      }
      __builtin_amdgcn_s_setprio(0);

      // ---- causal mask on the diagonal sub-tile (k-base == qrow0)
      if (diag) {
#pragma unroll
        for (int r = 0; r < 16; ++r) {
          int off = (r & 3) + 8 * (r >> 2) + 4 * hi;
          if (full) { if (off > q5) sc1[r] = MASKV; }
          else      { if (off > q5) sc0[r] = MASKV; }
        }
      }

      // ---- online softmax (1 q-row per lane), defer-max
      {
        float t8[8];
#pragma unroll
        for (int r = 0; r < 8; ++r) t8[r] = fmaxf(sc0[2 * r], sc0[2 * r + 1]);
        if (full) {
#pragma unroll
          for (int r = 0; r < 8; ++r)
            t8[r] = fmaxf(t8[r], fmaxf(sc1[2 * r], sc1[2 * r + 1]));
        }
        float t4a = fmaxf(t8[0], t8[1]), t4b = fmaxf(t8[2], t8[3]);
        float t4c = fmaxf(t8[4], t8[5]), t4d = fmaxf(t8[6], t8[7]);
        float pm = fmaxf(fmaxf(t4a, t4b), fmaxf(t4c, t4d));
        pm = fmaxf(pm, __shfl_xor(pm, 32, 64));
        if (!__all(pm <= mrow + 16.6f)) {     // T13 defer-max (P <= 8)
          float mn = fmaxf(mrow, pm);
          float corr = exp2f((mrow - mn) * EXPSCALE);
          mrow = mn;
          lrow *= corr;
#pragma unroll
          for (int r = 0; r < 16; ++r) { acc0[r] *= corr; acc1[r] *= corr; }
        }
        float mnS = mrow * EXPSCALE;
        float s8[8];
#pragma unroll
        for (int r = 0; r < 16; ++r)
          sc0[r] = exp2f(__builtin_fmaf(sc0[r], EXPSCALE, -mnS));
        if (full) {
#pragma unroll
          for (int r = 0; r < 16; ++r)
            sc1[r] = exp2f(__builtin_fmaf(sc1[r], EXPSCALE, -mnS));
#pragma unroll
          for (int r = 0; r < 8; ++r)
            s8[r] = (sc0[2 * r] + sc0[2 * r + 1]) + (sc1[2 * r] + sc1[2 * r + 1]);
        } else {
#pragma unroll
          for (int r = 0; r < 8; ++r) s8[r] = sc0[2 * r] + sc0[2 * r + 1];
        }
        float u4a = s8[0] + s8[1], u4b = s8[2] + s8[3];
        float u4c = s8[4] + s8[5], u4d = s8[6] + s8[7];
        float rs = (u4a + u4b) + (u4c + u4d);
        rs += __shfl_xor(rs, 32, 64);
        lrow += rs;
      }

      // ---- P -> bf16 B-frags via cvt_pk + permlane32_swap
      union U8 { unsigned u[4]; bf16x8 v; };
      bf16x8 pb[4];
      {
        unsigned w[4][2];
#pragma unroll
        for (int s = 0; s < 4; ++s) {
          w[s][0] = cvt_pk(sc0[4 * s + 0], sc0[4 * s + 1]);
          w[s][1] = cvt_pk(sc0[4 * s + 2], sc0[4 * s + 3]);
        }
        pl32swap(w[0][0], w[1][0]); pl32swap(w[0][1], w[1][1]);
        pl32swap(w[2][0], w[3][0]); pl32swap(w[2][1], w[3][1]);
        U8 u0; u0.u[0] = w[0][0]; u0.u[1] = w[0][1]; u0.u[2] = w[1][0]; u0.u[3] = w[1][1];
        U8 u1; u1.u[0] = w[2][0]; u1.u[1] = w[2][1]; u1.u[2] = w[3][0]; u1.u[3] = w[3][1];
        pb[0] = u0.v; pb[1] = u1.v;
      }
      if (full) {
        unsigned w[4][2];
#pragma unroll
        for (int s = 0; s < 4; ++s) {
          w[s][0] = cvt_pk(sc1[4 * s + 0], sc1[4 * s + 1]);
          w[s][1] = cvt_pk(sc1[4 * s + 2], sc1[4 * s + 3]);
        }
        pl32swap(w[0][0], w[1][0]); pl32swap(w[0][1], w[1][1]);
        pl32swap(w[2][0], w[3][0]); pl32swap(w[2][1], w[3][1]);
        U8 u0; u0.u[0] = w[0][0]; u0.u[1] = w[0][1]; u0.u[2] = w[1][0]; u0.u[3] = w[1][1];
        U8 u1; u1.u[0] = w[2][0]; u1.u[1] = w[2][1]; u1.u[2] = w[3][0]; u1.u[3] = w[3][1];
        pb[2] = u0.v; pb[3] = u1.v;
      }

      // ---- PV: O^T[d][q] += V^T-frag x P-frag
      const int nkb = full ? 4 : 2;
      __builtin_amdgcn_s_setprio(1);
      for (int kb = 0; kb < nkb; ++kb) {
        bf16x8 av0 = *(const bf16x8*)&Vc[q5 * 64 + (((2 * kb + hi) ^ (q5 & 7)) << 3)];
        acc0 = __builtin_amdgcn_mfma_f32_32x32x16_bf16(av0, pb[kb], acc0, 0, 0, 0);
        bf16x8 av1 = *(const bf16x8*)&Vc[(32 + q5) * 64 + (((2 * kb + hi) ^ (q5 & 7)) << 3)];
        acc1 = __builtin_amdgcn_mfma_f32_32x32x16_bf16(av1, pb[kb], acc1, 0, 0, 0);
      }
      __builtin_amdgcn_s_setprio(0);
    }
    __syncthreads();   // staging of t+1 complete; buf cur free for t+2
  }

  // ---- epilogue: O[q][d], d = dt*32 + 8s + 4hi + 0..3
  {
    float linv = 1.f / lrow;
    short* Op = O + (bS + qrow0 + q5) * D_MODEL + h * 64 + 4 * hi;
#pragma unroll
    for (int s = 0; s < 4; ++s) {
      uint2 w2;
      w2.x = cvt_pk(acc0[4 * s + 0] * linv, acc0[4 * s + 1] * linv);
      w2.y = cvt_pk(acc0[4 * s + 2] * linv, acc0[4 * s + 3] * linv);
      *(uint2*)(Op + 8 * s) = w2;
      uint2 w3;
      w3.x = cvt_pk(acc1[4 * s + 0] * linv, acc1[4 * s + 1] * linv);
      w3.y = cvt_pk(acc1[4 * s + 2] * linv, acc1[4 * s + 3] * linv);
      *(uint2*)(Op + 32 + 8 * s) = w3;
    }
  }
#undef STAGE
}

// ---------------------------------------------------------------- launch
extern "C" void kernel_launch(void* const* d_in, const int* in_sizes, int n_in,
                              void* d_out, int out_size, void* d_ws, size_t ws_size,
                              hipStream_t stream) {
  const float* X  = (const float*)d_in[0];
  const int* pos  = (const int*)d_in[1];
  const float* Wq = (const float*)d_in[2];
  const float* Wk = (const float*)d_in[3];
  const float* Wv = (const float*)d_in[4];
  const float* Wo = (const float*)d_in[5];

  char* ws = (char*)d_ws;
  short*  Xb  = (short*)(ws);                  // NX bf16
  short*  Wb  = (short*)(ws + 16777216);       // 4*WELEMS bf16
  short*  QKV = (short*)(ws + 25165824);       // 3*NX bf16 (Q,K,V)
  short*  Vt  = (short*)(ws + 75497472);       // NX bf16
  short*  Ob  = (short*)(ws + 92274688);       // NX bf16
  float2* tab = (float2*)(ws + 109051904);     // SEQ*32 float2

  prep_convert<<<12288, 256, 0, stream>>>(X, Wq, Wk, Wv, Wo, Xb, Wb);
  rope_table<<<256, 256, 0, stream>>>(pos, tab);
  gemm_bt<true><<<dim3(8, 64, 3), 256, 0, stream>>>(
      Xb, Wb, QKV, BS, D_MODEL, D_MODEL, WELEMS, NX);
  rope_apply<<<dim3(4096, 2, 1), 256, 0, stream>>>(QKV, tab);
  transpose_v<<<dim3(32, 16, 4), 256, 0, stream>>>(QKV + 2 * NX, Vt);
  flash_attn<<<dim3(16, 16, 4), 256, 0, stream>>>(QKV, QKV + NX, Vt, Ob);
  gemm_bt<false><<<dim3(8, 64, 1), 256, 0, stream>>>(
      Ob, Wb + 3 * WELEMS, d_out, BS, D_MODEL, D_MODEL, 0, 0);
}

// Round 11
// 349.543 us; speedup vs baseline: 2.9719x; 2.9719x over previous
//
#include <hip/hip_runtime.h>
#include <stdint.h>

#define D_MODEL 1024
#define NUM_HEADS 16
#define HEAD_DIM 64
#define BATCH 4
#define SEQ 2048
#define BS (BATCH*SEQ)                    // 8192 rows
#define NX ((size_t)BS*D_MODEL)           // 8388608 elements
#define WELEMS ((size_t)D_MODEL*D_MODEL)  // 1048576 elements

typedef short bf16x8 __attribute__((ext_vector_type(8)));
typedef short bf16x4 __attribute__((ext_vector_type(4)));
typedef float f32x4  __attribute__((ext_vector_type(4)));
typedef float f32x16 __attribute__((ext_vector_type(16)));

__device__ inline float b2f(short u) {
  unsigned x = ((unsigned)(unsigned short)u) << 16;
  union { unsigned u; float f; } c; c.u = x; return c.f;
}
__device__ inline short f2b(float f) {
  union { float f; unsigned u; } c; c.f = f;
  unsigned r = (c.u + 0x7FFFu + ((c.u >> 16) & 1u)) >> 16;
  return (short)r;
}
__device__ inline unsigned cvt_pk(float lo, float hi) {
  unsigned r;
  asm("v_cvt_pk_bf16_f32 %0, %1, %2" : "=v"(r) : "v"(lo), "v"(hi));
  return r;
}
// dst row1 (lanes 32-63) <-> src row0 (lanes 0-31); both operands modified.
__device__ inline void pl32swap(unsigned &a, unsigned &b) {
  asm("v_permlane32_swap_b32 %0, %1" : "+v"(a), "+v"(b));
}

typedef const __attribute__((address_space(1))) void* gas_t;
typedef __attribute__((address_space(3))) void*       las_t;
__device__ inline void gload16(const void* g, void* l) {
  __builtin_amdgcn_global_load_lds((gas_t)(uintptr_t)g,
                                   (las_t)(uint32_t)(uintptr_t)l, 16, 0, 0);
}

// ---------------------------------------------------------------- prep
__global__ __launch_bounds__(256) void prep_convert(
    const float* __restrict__ X,
    const float* __restrict__ Wq, const float* __restrict__ Wk,
    const float* __restrict__ Wv, const float* __restrict__ Wo,
    short* __restrict__ Xb, short* __restrict__ Wb)
{
  size_t i = ((size_t)blockIdx.x * 256 + threadIdx.x) * 4;
  const float* src; short* dst; size_t off;
  if (i < NX) { src = X; dst = Xb; off = i; }
  else {
    size_t wi = i - NX;
    int w = (int)(wi >> 20);
    off = wi & (WELEMS - 1);
    src = (w == 0) ? Wq : (w == 1) ? Wk : (w == 2) ? Wv : Wo;
    dst = Wb + (size_t)w * WELEMS;
  }
  float4 v = *(const float4*)(src + off);
  bf16x4 o;
  o[0] = f2b(v.x); o[1] = f2b(v.y); o[2] = f2b(v.z); o[3] = f2b(v.w);
  *(bf16x4*)(dst + off) = o;
}

__global__ __launch_bounds__(256) void rope_table(
    const int* __restrict__ pos, float2* __restrict__ tab)
{
  int idx = blockIdx.x * 256 + threadIdx.x;   // 65536 total
  int s = idx >> 5, i = idx & 31;
  float p = (float)pos[s];
  float inv = exp2f(-0.41524101186098287f * (float)i);
  float a = p * inv;
  tab[idx] = make_float2(cosf(a), sinf(a));
}

// ---------------------------------------------------------------- GEMM
template<bool BF16OUT>
__global__ __launch_bounds__(256) void gemm_bt(
    const short* __restrict__ A, const short* __restrict__ Bw,
    void* __restrict__ outv, const int M, const int N, const int K,
    const size_t strideB, const size_t strideOut)
{
  __shared__ short Ash[128 * 32];
  __shared__ short Bsh[128 * 32];
  const int tid = threadIdx.x;
  const int wid = tid >> 6, lane = tid & 63;
  const int g = lane >> 4, li = lane & 15;
  const int row0 = blockIdx.y * 128, col0 = blockIdx.x * 128;
  const int wr = wid >> 1, wc = wid & 1;
  const short* Bz = Bw + (size_t)blockIdx.z * strideB;

  const short* Ag = A  + (size_t)(row0 + wid * 32 + (lane >> 2)) * K + (lane & 3) * 8;
  const short* Bg = Bz + (size_t)(col0 + wid * 32 + (lane >> 2)) * K + (lane & 3) * 8;
  short* lA = &Ash[wid * 1024];
  short* lB = &Bsh[wid * 1024];

  f32x4 acc[4][4];
#pragma unroll
  for (int i = 0; i < 4; ++i)
#pragma unroll
    for (int j = 0; j < 4; ++j) acc[i][j] = (f32x4){0.f, 0.f, 0.f, 0.f};

  for (int kt = 0; kt < K; kt += 32) {
    gload16(Ag + kt,                 lA);
    gload16(Ag + kt + (size_t)16*K,  lA + 512);
    gload16(Bg + kt,                 lB);
    gload16(Bg + kt + (size_t)16*K,  lB + 512);
    __syncthreads();
    bf16x8 af[4], bfv[4];
#pragma unroll
    for (int mm = 0; mm < 4; ++mm)
      af[mm] = *(const bf16x8*)&Ash[(wr * 64 + mm * 16 + li) * 32 + g * 8];
#pragma unroll
    for (int nn = 0; nn < 4; ++nn)
      bfv[nn] = *(const bf16x8*)&Bsh[(wc * 64 + nn * 16 + li) * 32 + g * 8];
#pragma unroll
    for (int mm = 0; mm < 4; ++mm)
#pragma unroll
      for (int nn = 0; nn < 4; ++nn)
        acc[mm][nn] = __builtin_amdgcn_mfma_f32_16x16x32_bf16(
            af[mm], bfv[nn], acc[mm][nn], 0, 0, 0);
    __syncthreads();
  }

  if (BF16OUT) {
    short* out = (short*)outv + (size_t)blockIdx.z * strideOut;
#pragma unroll
    for (int mm = 0; mm < 4; ++mm)
#pragma unroll
      for (int nn = 0; nn < 4; ++nn)
#pragma unroll
        for (int j = 0; j < 4; ++j) {
          int r = row0 + wr * 64 + mm * 16 + g * 4 + j;
          int c = col0 + wc * 64 + nn * 16 + li;
          out[(size_t)r * N + c] = f2b(acc[mm][nn][j]);
        }
  } else {
    float* out = (float*)outv;
#pragma unroll
    for (int mm = 0; mm < 4; ++mm)
#pragma unroll
      for (int nn = 0; nn < 4; ++nn)
#pragma unroll
        for (int j = 0; j < 4; ++j) {
          int r = row0 + wr * 64 + mm * 16 + g * 4 + j;
          int c = col0 + wc * 64 + nn * 16 + li;
          out[(size_t)r * N + c] = acc[mm][nn][j];
        }
  }
}

// ---------------------------------------------------------------- RoPE
__global__ __launch_bounds__(256) void rope_apply(
    short* __restrict__ QK, const float2* __restrict__ tab)
{
  size_t idx = (size_t)blockIdx.x * 256 + threadIdx.x;
  short* base = QK + (size_t)blockIdx.y * NX + idx * 8;
  size_t e = idx * 8;
  int s  = (int)((e >> 10) & (SEQ - 1));
  int dd = (int)(e & (D_MODEL - 1));
  int i0 = (dd & 63) >> 1;
  const float2* tp = tab + s * 32 + i0;
  bf16x8 v = *(bf16x8*)base;
#pragma unroll
  for (int k = 0; k < 4; ++k) {
    float2 cs = tp[k];
    float ev = b2f(v[2 * k]), ov = b2f(v[2 * k + 1]);
    v[2 * k]     = f2b(ev * cs.x - ov * cs.y);
    v[2 * k + 1] = f2b(ev * cs.y + ov * cs.x);
  }
  *(bf16x8*)base = v;
}

// ---------------------------------------------------------------- V^T
__global__ __launch_bounds__(256) void transpose_v(
    const short* __restrict__ V, short* __restrict__ Vt)
{
  __shared__ short tile[64][72];
  const int s0 = blockIdx.x * 64, h = blockIdx.y, b = blockIdx.z;
  const int t = threadIdx.x;
  const short* src = V + ((size_t)(b * SEQ + s0)) * D_MODEL + h * 64;
#pragma unroll
  for (int it = 0; it < 2; ++it) {
    int r = it * 32 + (t >> 3), c0 = (t & 7) * 8;
    *(bf16x8*)&tile[r][c0] = *(const bf16x8*)(src + (size_t)r * D_MODEL + c0);
  }
  __syncthreads();
  short* dst = Vt + ((size_t)(b * NUM_HEADS + h) * 64) * SEQ + s0;
#pragma unroll
  for (int it = 0; it < 2; ++it) {
    int d = it * 32 + (t >> 3), sOff = (t & 7) * 8;
    bf16x8 v;
#pragma unroll
    for (int j = 0; j < 8; ++j) v[j] = tile[sOff + j][d];
    *(bf16x8*)(dst + (size_t)d * SEQ + sOff) = v;
  }
}

// ---------------------------------------------------------------- flash v7
// = v6 with the PV loop STATICALLY indexed (rule #20): v5/v6's
// `for(kb<nkb) ... pb[kb]` with runtime nkb put pb[4] in SCRATCH ->
// every tile-iter round-tripped P through local memory (5x slowdown,
// VGPR_Count=68 signature). pb is now 4 named values; kb unrolled by hand.
#define EXPSCALE 0.18033688011112043f   // log2(e) / sqrt(64)
#define MASKV   -30000.0f

__global__ __launch_bounds__(256, 3) void flash_attn(
    const short* __restrict__ Q, const short* __restrict__ K,
    const short* __restrict__ Vt, short* __restrict__ O)
{
  __shared__ short Ksh[2][64 * 64];   // 8KB per buf
  __shared__ short Vsh[2][64 * 64];
  const int qtb = 15 - (int)blockIdx.x;            // long blocks first
  const int h = blockIdx.y, b = blockIdx.z;
  const int tid = threadIdx.x;
  const int wid = tid >> 6, lane = tid & 63;
  const int q5 = lane & 31, hi = lane >> 5;
  const int qrow0 = qtb * 128 + wid * 32;
  const int tmaxBlk = 2 * qtb + 1;
  const int wtmax = (qrow0 + 31) >> 6;
  const size_t bS = (size_t)b * SEQ;

  const short* Kb = K  + bS * D_MODEL + h * 64;
  const short* Vb = Vt + (size_t)(b * NUM_HEADS + h) * 64 * SEQ;

  // staging geometry (pre-swizzled global source; LDS dest linear)
  const int srr = lane >> 3;               // 0..7
  const int cs  = (lane & 7) ^ srr;        // source chunk
  const int rB  = wid * 8 + srr;

#define STAGE(buf, t) {                                                      \
    const size_t kr0 = (size_t)((t) * 64 + rB) * D_MODEL + cs * 8;           \
    const size_t kr1 = (size_t)((t) * 64 + rB + 32) * D_MODEL + cs * 8;      \
    gload16(Kb + kr0, &Ksh[buf][(wid * 8) * 64]);                            \
    gload16(Kb + kr1, &Ksh[buf][(32 + wid * 8) * 64]);                       \
    const size_t vr0 = (size_t)rB * SEQ + (t) * 64 + cs * 8;                 \
    const size_t vr1 = (size_t)(rB + 32) * SEQ + (t) * 64 + cs * 8;          \
    gload16(Vb + vr0, &Vsh[buf][(wid * 8) * 64]);                            \
    gload16(Vb + vr1, &Vsh[buf][(32 + wid * 8) * 64]);                       \
  }

  // Q B-frags: qb[dblk][e] = Q[qrow0+q5][dblk*16 + 8*hi + e]
  bf16x8 qb0, qb1, qb2, qb3;
  {
    const short* Qp = Q + (bS + qrow0 + q5) * D_MODEL + h * 64 + hi * 8;
    qb0 = *(const bf16x8*)(Qp);
    qb1 = *(const bf16x8*)(Qp + 16);
    qb2 = *(const bf16x8*)(Qp + 32);
    qb3 = *(const bf16x8*)(Qp + 48);
  }

  f32x16 acc0, acc1;
#pragma unroll
  for (int r = 0; r < 16; ++r) { acc0[r] = 0.f; acc1[r] = 0.f; }
  float mrow = MASKV, lrow = 0.f;

  STAGE(0, 0);
  __syncthreads();

  for (int t = 0; t <= tmaxBlk; ++t) {
    const int cur = t & 1;
    if (t < tmaxBlk) STAGE(cur ^ 1, t + 1);

    if (t <= wtmax) {
      const short* Kc = &Ksh[cur][0];
      const short* Vc = &Vsh[cur][0];
      const bool diag = (t == wtmax);
      const bool full = !diag || (wid & 1);   // even waves: n=1 all-masked

      // ---- QK^T: S^T rows k, col q (lane owns q = q5)
      f32x16 sc0, sc1;
#pragma unroll
      for (int r = 0; r < 16; ++r) { sc0[r] = 0.f; sc1[r] = 0.f; }
      __builtin_amdgcn_s_setprio(1);
      {
        bf16x8 ak;
        ak = *(const bf16x8*)&Kc[q5 * 64 + (((0 + hi) ^ (q5 & 7)) << 3)];
        sc0 = __builtin_amdgcn_mfma_f32_32x32x16_bf16(ak, qb0, sc0, 0, 0, 0);
        ak = *(const bf16x8*)&Kc[q5 * 64 + (((2 + hi) ^ (q5 & 7)) << 3)];
        sc0 = __builtin_amdgcn_mfma_f32_32x32x16_bf16(ak, qb1, sc0, 0, 0, 0);
        ak = *(const bf16x8*)&Kc[q5 * 64 + (((4 + hi) ^ (q5 & 7)) << 3)];
        sc0 = __builtin_amdgcn_mfma_f32_32x32x16_bf16(ak, qb2, sc0, 0, 0, 0);
        ak = *(const bf16x8*)&Kc[q5 * 64 + (((6 + hi) ^ (q5 & 7)) << 3)];
        sc0 = __builtin_amdgcn_mfma_f32_32x32x16_bf16(ak, qb3, sc0, 0, 0, 0);
      }
      if (full) {
        bf16x8 ak;
        ak = *(const bf16x8*)&Kc[(32 + q5) * 64 + (((0 + hi) ^ (q5 & 7)) << 3)];
        sc1 = __builtin_amdgcn_mfma_f32_32x32x16_bf16(ak, qb0, sc1, 0, 0, 0);
        ak = *(const bf16x8*)&Kc[(32 + q5) * 64 + (((2 + hi) ^ (q5 & 7)) << 3)];
        sc1 = __builtin_amdgcn_mfma_f32_32x32x16_bf16(ak, qb1, sc1, 0, 0, 0);
        ak = *(const bf16x8*)&Kc[(32 + q5) * 64 + (((4 + hi) ^ (q5 & 7)) << 3)];
        sc1 = __builtin_amdgcn_mfma_f32_32x32x16_bf16(ak, qb2, sc1, 0, 0, 0);
        ak = *(const bf16x8*)&Kc[(32 + q5) * 64 + (((6 + hi) ^ (q5 & 7)) << 3)];
        sc1 = __builtin_amdgcn_mfma_f32_32x32x16_bf16(ak, qb3, sc1, 0, 0, 0);
      }
      __builtin_amdgcn_s_setprio(0);

      // ---- causal mask on the diagonal sub-tile (k-base == qrow0)
      if (diag) {
#pragma unroll
        for (int r = 0; r < 16; ++r) {
          int off = (r & 3) + 8 * (r >> 2) + 4 * hi;
          if (full) { if (off > q5) sc1[r] = MASKV; }
          else      { if (off > q5) sc0[r] = MASKV; }
        }
      }

      // ---- online softmax (1 q-row per lane), defer-max
      {
        float t8[8];
#pragma unroll
        for (int r = 0; r < 8; ++r) t8[r] = fmaxf(sc0[2 * r], sc0[2 * r + 1]);
        if (full) {
#pragma unroll
          for (int r = 0; r < 8; ++r)
            t8[r] = fmaxf(t8[r], fmaxf(sc1[2 * r], sc1[2 * r + 1]));
        }
        float t4a = fmaxf(t8[0], t8[1]), t4b = fmaxf(t8[2], t8[3]);
        float t4c = fmaxf(t8[4], t8[5]), t4d = fmaxf(t8[6], t8[7]);
        float pm = fmaxf(fmaxf(t4a, t4b), fmaxf(t4c, t4d));
        pm = fmaxf(pm, __shfl_xor(pm, 32, 64));
        if (!__all(pm <= mrow + 16.6f)) {     // T13 defer-max (P <= 8)
          float mn = fmaxf(mrow, pm);
          float corr = exp2f((mrow - mn) * EXPSCALE);
          mrow = mn;
          lrow *= corr;
#pragma unroll
          for (int r = 0; r < 16; ++r) { acc0[r] *= corr; acc1[r] *= corr; }
        }
        float mnS = mrow * EXPSCALE;
        float s8[8];
#pragma unroll
        for (int r = 0; r < 16; ++r)
          sc0[r] = exp2f(__builtin_fmaf(sc0[r], EXPSCALE, -mnS));
        if (full) {
#pragma unroll
          for (int r = 0; r < 16; ++r)
            sc1[r] = exp2f(__builtin_fmaf(sc1[r], EXPSCALE, -mnS));
#pragma unroll
          for (int r = 0; r < 8; ++r)
            s8[r] = (sc0[2 * r] + sc0[2 * r + 1]) + (sc1[2 * r] + sc1[2 * r + 1]);
        } else {
#pragma unroll
          for (int r = 0; r < 8; ++r) s8[r] = sc0[2 * r] + sc0[2 * r + 1];
        }
        float u4a = s8[0] + s8[1], u4b = s8[2] + s8[3];
        float u4c = s8[4] + s8[5], u4d = s8[6] + s8[7];
        float rs = (u4a + u4b) + (u4c + u4d);
        rs += __shfl_xor(rs, 32, 64);
        lrow += rs;
      }

      // ---- P -> bf16 B-frags via cvt_pk + permlane32_swap (named regs)
      union U8 { unsigned u[4]; bf16x8 v; };
      bf16x8 pb0, pb1, pb2, pb3;
      {
        unsigned w00 = cvt_pk(sc0[0],  sc0[1]),  w01 = cvt_pk(sc0[2],  sc0[3]);
        unsigned w10 = cvt_pk(sc0[4],  sc0[5]),  w11 = cvt_pk(sc0[6],  sc0[7]);
        unsigned w20 = cvt_pk(sc0[8],  sc0[9]),  w21 = cvt_pk(sc0[10], sc0[11]);
        unsigned w30 = cvt_pk(sc0[12], sc0[13]), w31 = cvt_pk(sc0[14], sc0[15]);
        pl32swap(w00, w10); pl32swap(w01, w11);
        pl32swap(w20, w30); pl32swap(w21, w31);
        U8 u0; u0.u[0] = w00; u0.u[1] = w01; u0.u[2] = w10; u0.u[3] = w11;
        U8 u1; u1.u[0] = w20; u1.u[1] = w21; u1.u[2] = w30; u1.u[3] = w31;
        pb0 = u0.v; pb1 = u1.v;
      }
      if (full) {
        unsigned w00 = cvt_pk(sc1[0],  sc1[1]),  w01 = cvt_pk(sc1[2],  sc1[3]);
        unsigned w10 = cvt_pk(sc1[4],  sc1[5]),  w11 = cvt_pk(sc1[6],  sc1[7]);
        unsigned w20 = cvt_pk(sc1[8],  sc1[9]),  w21 = cvt_pk(sc1[10], sc1[11]);
        unsigned w30 = cvt_pk(sc1[12], sc1[13]), w31 = cvt_pk(sc1[14], sc1[15]);
        pl32swap(w00, w10); pl32swap(w01, w11);
        pl32swap(w20, w30); pl32swap(w21, w31);
        U8 u0; u0.u[0] = w00; u0.u[1] = w01; u0.u[2] = w10; u0.u[3] = w11;
        U8 u1; u1.u[0] = w20; u1.u[1] = w21; u1.u[2] = w30; u1.u[3] = w31;
        pb2 = u0.v; pb3 = u1.v;
      }

      // ---- PV: O^T[d][q] += V^T-frag x P-frag (static unroll, named pb)
      __builtin_amdgcn_s_setprio(1);
      {
        bf16x8 av;
        av = *(const bf16x8*)&Vc[q5 * 64 + (((0 + hi) ^ (q5 & 7)) << 3)];
        acc0 = __builtin_amdgcn_mfma_f32_32x32x16_bf16(av, pb0, acc0, 0, 0, 0);
        av = *(const bf16x8*)&Vc[(32 + q5) * 64 + (((0 + hi) ^ (q5 & 7)) << 3)];
        acc1 = __builtin_amdgcn_mfma_f32_32x32x16_bf16(av, pb0, acc1, 0, 0, 0);
        av = *(const bf16x8*)&Vc[q5 * 64 + (((2 + hi) ^ (q5 & 7)) << 3)];
        acc0 = __builtin_amdgcn_mfma_f32_32x32x16_bf16(av, pb1, acc0, 0, 0, 0);
        av = *(const bf16x8*)&Vc[(32 + q5) * 64 + (((2 + hi) ^ (q5 & 7)) << 3)];
        acc1 = __builtin_amdgcn_mfma_f32_32x32x16_bf16(av, pb1, acc1, 0, 0, 0);
      }
      if (full) {
        bf16x8 av;
        av = *(const bf16x8*)&Vc[q5 * 64 + (((4 + hi) ^ (q5 & 7)) << 3)];
        acc0 = __builtin_amdgcn_mfma_f32_32x32x16_bf16(av, pb2, acc0, 0, 0, 0);
        av = *(const bf16x8*)&Vc[(32 + q5) * 64 + (((4 + hi) ^ (q5 & 7)) << 3)];
        acc1 = __builtin_amdgcn_mfma_f32_32x32x16_bf16(av, pb2, acc1, 0, 0, 0);
        av = *(const bf16x8*)&Vc[q5 * 64 + (((6 + hi) ^ (q5 & 7)) << 3)];
        acc0 = __builtin_amdgcn_mfma_f32_32x32x16_bf16(av, pb3, acc0, 0, 0, 0);
        av = *(const bf16x8*)&Vc[(32 + q5) * 64 + (((6 + hi) ^ (q5 & 7)) << 3)];
        acc1 = __builtin_amdgcn_mfma_f32_32x32x16_bf16(av, pb3, acc1, 0, 0, 0);
      }
      __builtin_amdgcn_s_setprio(0);
    }
    __syncthreads();   // staging of t+1 complete; buf cur free for t+2
  }

  // ---- epilogue: O[q][d], d = dt*32 + 8s + 4hi + 0..3
  {
    float linv = 1.f / lrow;
    short* Op = O + (bS + qrow0 + q5) * D_MODEL + h * 64 + 4 * hi;
#pragma unroll
    for (int s = 0; s < 4; ++s) {
      uint2 w2;
      w2.x = cvt_pk(acc0[4 * s + 0] * linv, acc0[4 * s + 1] * linv);
      w2.y = cvt_pk(acc0[4 * s + 2] * linv, acc0[4 * s + 3] * linv);
      *(uint2*)(Op + 8 * s) = w2;
      uint2 w3;
      w3.x = cvt_pk(acc1[4 * s + 0] * linv, acc1[4 * s + 1] * linv);
      w3.y = cvt_pk(acc1[4 * s + 2] * linv, acc1[4 * s + 3] * linv);
      *(uint2*)(Op + 32 + 8 * s) = w3;
    }
  }
#undef STAGE
}

// ---------------------------------------------------------------- launch
extern "C" void kernel_launch(void* const* d_in, const int* in_sizes, int n_in,
                              void* d_out, int out_size, void* d_ws, size_t ws_size,
                              hipStream_t stream) {
  const float* X  = (const float*)d_in[0];
  const int* pos  = (const int*)d_in[1];
  const float* Wq = (const float*)d_in[2];
  const float* Wk = (const float*)d_in[3];
  const float* Wv = (const float*)d_in[4];
  const float* Wo = (const float*)d_in[5];

  char* ws = (char*)d_ws;
  short*  Xb  = (short*)(ws);                  // NX bf16
  short*  Wb  = (short*)(ws + 16777216);       // 4*WELEMS bf16
  short*  QKV = (short*)(ws + 25165824);       // 3*NX bf16 (Q,K,V)
  short*  Vt  = (short*)(ws + 75497472);       // NX bf16
  short*  Ob  = (short*)(ws + 92274688);       // NX bf16
  float2* tab = (float2*)(ws + 109051904);     // SEQ*32 float2

  prep_convert<<<12288, 256, 0, stream>>>(X, Wq, Wk, Wv, Wo, Xb, Wb);
  rope_table<<<256, 256, 0, stream>>>(pos, tab);
  gemm_bt<true><<<dim3(8, 64, 3), 256, 0, stream>>>(
      Xb, Wb, QKV, BS, D_MODEL, D_MODEL, WELEMS, NX);
  rope_apply<<<dim3(4096, 2, 1), 256, 0, stream>>>(QKV, tab);
  transpose_v<<<dim3(32, 16, 4), 256, 0, stream>>>(QKV + 2 * NX, Vt);
  flash_attn<<<dim3(16, 16, 4), 256, 0, stream>>>(QKV, QKV + NX, Vt, Ob);
  gemm_bt<false><<<dim3(8, 64, 1), 256, 0, stream>>>(
      Ob, Wb + 3 * WELEMS, d_out, BS, D_MODEL, D_MODEL, 0, 0);
}